// Round 14
// baseline (81.871 us; speedup 1.0000x reference)
//
#include <hip/hip_runtime.h>

// Problem constants (fixed by the reference setup)
#define Bd 4
#define Cd 64
#define HWp 262144           // 512*512 = 2^18 pixels per image
#define NSd 2048
#define NLd 1000

#define NWIN   256           // windows total (64 per image)
#define PXW    4096          // pixels per window
#define NSL    16            // channel slices (4 ch each)
#define CSL    4             // channels per slice
#define SPB    8             // slices per block (2 blocks per window)
#define PU32   2000          // u32 per partial slice-row (1000 labels x uint2)

typedef float __attribute__((ext_vector_type(4))) floatx4;

// ===========================================================================
// FAST PATH:
//   rank   : per-window {hist -> scan -> window-local ranks} ONCE
//            (writes rank / blockCnt / blockStart)
//   fused  : grid (2, 256), 2 blocks/CU. Loads precomputed ranks (int4) and
//            cnt/start; 8 slices {scatter bf16x4 rows to LDS -> per-label
//            lane sums -> bf16 partial store}. 16 barriers (was ~38).
//   combine: reduce 64 windows -> means (f32 accum, fused divide)
//   gather : edge endpoint means + edge weights
// ws layout (4B units):
//   partial   [NWIN*NSL*PU32] u32    bf16-pair label sums
//   blockCnt  [NWIN*NL]       int
//   blockSt   [NWIN*NL]       int
//   rank      [NWIN*PXW]      int    window-local sorted position per pixel
//   means     [B*NL*C]        float
// ===========================================================================
#define OFF_PART  0
#define OFF_BCNT  (NWIN * NSL * PU32)
#define OFF_BST   (OFF_BCNT + NWIN * NLd)
#define OFF_RANK  (OFF_BST + NWIN * NLd)
#define OFF_MEANS (OFF_RANK + NWIN * PXW)
#define WS_ELEMS  (OFF_MEANS + Bd * NLd * Cd)

__device__ __forceinline__ unsigned short f2bf(float f) {
    unsigned u = __float_as_uint(f);
    u += 0x7FFFu + ((u >> 16) & 1u);          // round-to-nearest-even
    return (unsigned short)(u >> 16);
}
__device__ __forceinline__ unsigned pack2(float lo, float hi) {
    return ((unsigned)f2bf(hi) << 16) | (unsigned)f2bf(lo);
}
__device__ __forceinline__ float bflo(unsigned u) { return __uint_as_float(u << 16); }
__device__ __forceinline__ float bfhi(unsigned u) { return __uint_as_float(u & 0xFFFF0000u); }
__device__ __forceinline__ int clampl(int l) {
    return (l < 0) ? 0 : (l >= NLd ? NLd - 1 : l);
}

// ---------------------------------------------------------------------------
// 1) rank kernel: per-window sort metadata. grid = NWIN, block = 1024.
// ---------------------------------------------------------------------------
__global__ __launch_bounds__(1024)
void rank_kernel(const int* __restrict__ lab, int* __restrict__ blockCnt,
                 int* __restrict__ blockSt, int* __restrict__ rank) {
    __shared__ int h[1024];          // hist -> scan -> cursor (reused)
    const int tid = threadIdx.x;
    const int w   = blockIdx.x;
    const int b   = w >> 6;
    const int p0  = (w & 63) * PXW;

    h[tid] = 0;
    __syncthreads();

    const int4 lv = ((const int4*)(lab + ((size_t)b << 18) + p0))[tid];
    const int l0 = clampl(lv.x), l1 = clampl(lv.y),
              l2 = clampl(lv.z), l3 = clampl(lv.w);
    atomicAdd(&h[l0], 1);
    atomicAdd(&h[l1], 1);
    atomicAdd(&h[l2], 1);
    atomicAdd(&h[l3], 1);
    __syncthreads();

    const int myCnt = h[tid];
    if (tid < NLd) blockCnt[(size_t)w * NLd + tid] = myCnt;
    for (int off = 1; off < 1024; off <<= 1) {
        int t = (tid >= off) ? h[tid - off] : 0;
        __syncthreads();
        h[tid] += t;
        __syncthreads();
    }
    const int myst = h[tid] - myCnt;
    if (tid < NLd) blockSt[(size_t)w * NLd + tid] = myst;
    __syncthreads();
    h[tid] = myst;                   // cursor init
    __syncthreads();

    int4 rv;
    rv.x = atomicAdd(&h[l0], 1) & (PXW - 1);
    rv.y = atomicAdd(&h[l1], 1) & (PXW - 1);
    rv.z = atomicAdd(&h[l2], 1) & (PXW - 1);
    rv.w = atomicAdd(&h[l3], 1) & (PXW - 1);
    ((int4*)(rank + ((size_t)w << 12)))[tid] = rv;
}

// ---------------------------------------------------------------------------
// 2) fused kernel. grid = (2, NWIN), block = 1024 (thread owns 4 px).
//    LDS 32KB, VGPR forced <=64 -> 2 blocks/CU co-resident.
// ---------------------------------------------------------------------------
__global__ __launch_bounds__(1024, 8)
void fused_kernel(const float* __restrict__ x, const int* __restrict__ rank,
                  const int* __restrict__ blockCnt, const int* __restrict__ blockSt,
                  unsigned* __restrict__ partial) {
    __shared__ uint2 ordered[PXW];   // 32 KB: rank-ordered bf16x4 pixel rows

    const int tid  = threadIdx.x;
    const int half = blockIdx.x;     // 0..1 (slice group)
    const int w    = blockIdx.y;     // 0..255 (window)
    const int b    = w >> 6;
    const int p0   = (w & 63) * PXW;

    // precomputed window-local ranks of my 4 pixels (coalesced int4)
    int4 rv = ((const int4*)(rank + ((size_t)w << 12)))[tid];
    const int r0 = rv.x & (PXW - 1), r1 = rv.y & (PXW - 1),
              r2 = rv.z & (PXW - 1), r3 = rv.w & (PXW - 1);

    // my label's run (coalesced for tid < 1000)
    int myCnt = 0, myst = 0;
    if (tid < NLd) {
        myCnt = blockCnt[(size_t)w * NLd + tid];
        myst  = blockSt [(size_t)w * NLd + tid];
        if (myst < 0) myst = 0; if (myst > PXW) myst = PXW;
        if (myCnt < 0) myCnt = 0;
        if (myCnt > PXW - myst) myCnt = PXW - myst;
    }

    const float* __restrict__ xs =
        x + (((size_t)b * Cd + half * (SPB * CSL)) << 18) + p0 + 4 * tid;
    unsigned* __restrict__ pout =
        partial + ((size_t)w * NSL + half * SPB) * PU32;

    // prologue: load + pack local slice 0
    floatx4 v0, v1, v2, v3;
    v0 = __builtin_nontemporal_load((const floatx4*)(xs + ((size_t)0 << 18)));
    v1 = __builtin_nontemporal_load((const floatx4*)(xs + ((size_t)1 << 18)));
    v2 = __builtin_nontemporal_load((const floatx4*)(xs + ((size_t)2 << 18)));
    v3 = __builtin_nontemporal_load((const floatx4*)(xs + ((size_t)3 << 18)));
    uint2 pk0, pk1, pk2, pk3;
    pk0.x = pack2(v0[0], v1[0]); pk0.y = pack2(v2[0], v3[0]);
    pk1.x = pack2(v0[1], v1[1]); pk1.y = pack2(v2[1], v3[1]);
    pk2.x = pack2(v0[2], v1[2]); pk2.y = pack2(v2[2], v3[2]);
    pk3.x = pack2(v0[3], v1[3]); pk3.y = pack2(v2[3], v3[3]);

    for (int s = 0; s < SPB; ++s) {
        __syncthreads();                 // previous slice's sums complete
        ordered[r0] = pk0;
        ordered[r1] = pk1;
        ordered[r2] = pk2;
        ordered[r3] = pk3;
        if (s + 1 < SPB) {               // issue next slice's loads now
            const float* nb = xs + (((size_t)((s + 1) * CSL)) << 18);
            v0 = __builtin_nontemporal_load((const floatx4*)(nb + ((size_t)0 << 18)));
            v1 = __builtin_nontemporal_load((const floatx4*)(nb + ((size_t)1 << 18)));
            v2 = __builtin_nontemporal_load((const floatx4*)(nb + ((size_t)2 << 18)));
            v3 = __builtin_nontemporal_load((const floatx4*)(nb + ((size_t)3 << 18)));
        }
        __syncthreads();                 // scatter visible

        if (tid < NLd) {
            float a0 = 0, a1 = 0, a2 = 0, a3 = 0;
            for (int i = 0; i < myCnt; ++i) {
                uint2 u = ordered[(myst + i) & (PXW - 1)];
                a0 += bflo(u.x); a1 += bfhi(u.x);
                a2 += bflo(u.y); a3 += bfhi(u.y);
            }
            uint2 o; o.x = pack2(a0, a1); o.y = pack2(a2, a3);
            *(uint2*)(pout + (size_t)s * PU32 + tid * 2) = o;
        }
        if (s + 1 < SPB) {               // pack after sums (waits on loads)
            pk0.x = pack2(v0[0], v1[0]); pk0.y = pack2(v2[0], v3[0]);
            pk1.x = pack2(v0[1], v1[1]); pk1.y = pack2(v2[1], v3[1]);
            pk2.x = pack2(v0[2], v1[2]); pk2.y = pack2(v2[2], v3[2]);
            pk3.x = pack2(v0[3], v1[3]); pk3.y = pack2(v2[3], v3[3]);
        }
    }
}

// ---------------------------------------------------------------------------
// 3) combine: reduce 64 windows -> means[b][l][c], f32 accumulate.
//    grid = (63, B) x 256 thr; tid -> (s = tid>>4, ll = tid&15).
// ---------------------------------------------------------------------------
__global__ __launch_bounds__(256)
void combine_kernel(const unsigned* __restrict__ partial,
                    const int* __restrict__ blockCnt,
                    float* __restrict__ means) {
    __shared__ float ninv[16];
    const int tid = threadIdx.x;
    const int b   = blockIdx.y;
    const int l0  = blockIdx.x * 16;
    const int s   = tid >> 4;       // slice 0..15
    const int ll  = tid & 15;       // label within group
    const int l   = l0 + ll;

    if (tid < 16) {
        const int li = (l0 + tid < NLd) ? (l0 + tid) : (NLd - 1);
        int n = 0;
        for (int g = 0; g < 64; ++g)
            n += blockCnt[(size_t)(b * 64 + g) * NLd + li];
        ninv[tid] = 1.0f / (float)(n > 0 ? n : 1);
    }
    __syncthreads();

    if (l < NLd) {
        float r0 = 0, r1 = 0, r2 = 0, r3 = 0;
        const unsigned* __restrict__ pb =
            partial + ((size_t)(b * 64) * NSL + s) * PU32 + l * 2;
        for (int g = 0; g < 64; ++g) {
            uint2 p = *(const uint2*)(pb + (size_t)g * NSL * PU32);
            r0 += bflo(p.x); r1 += bfhi(p.x);
            r2 += bflo(p.y); r3 += bfhi(p.y);
        }
        const float sc = ninv[ll];
        float4 o; o.x = r0 * sc; o.y = r1 * sc; o.z = r2 * sc; o.w = r3 * sc;
        *(float4*)(means + (((size_t)(b * NLd + l)) << 6) + s * 4) = o;
    }
}

// ---------------------------------------------------------------------------
// 4) gather means at edge endpoints + copy edge weights.
// ---------------------------------------------------------------------------
__global__ __launch_bounds__(256)
void gather_kernel(const float* __restrict__ means,
                   const int* __restrict__ edges,
                   const float* __restrict__ ew,
                   float* __restrict__ out) {
    const int t  = blockIdx.x * 256 + threadIdx.x;   // 0 .. B*NS*C-1
    const int bs = t >> 6;                           // b*NS + s
    const int c  = t & 63;
    const int b  = bs >> 11;                         // NS = 2048

    const int la = clampl(edges[bs * 2 + 0]);
    const int lb = clampl(edges[bs * 2 + 1]);

    out[t] = means[((size_t)(b * NLd + la) << 6) + c];
    out[(size_t)Bd * NSd * Cd + t] = means[((size_t)(b * NLd + lb) << 6) + c];
    if (t < Bd * NSd)
        out[2 * (size_t)Bd * NSd * Cd + t] = ew[t];
}

// ===========================================================================
// FALLBACK PATH (R1 design, known-good 371 us; needs ~1 MB ws)
// ===========================================================================
#define WS_FB_ELEMS (Bd * Cd * NLd + Bd * NLd)

__global__ __launch_bounds__(256)
void fb_sums_kernel(const float* __restrict__ x, const int* __restrict__ lab,
                    float* __restrict__ sums) {
    __shared__ float lsum[NLd];
    const int tid   = threadIdx.x;
    const int chunk = blockIdx.x;
    const int c     = blockIdx.y;
    const int b     = blockIdx.z;

    for (int l = tid; l < NLd; l += 256) lsum[l] = 0.0f;
    __syncthreads();

    const float4* __restrict__ xp =
        (const float4*)x + (size_t)(b * Cd + c) * (HWp / 4);
    const int4* __restrict__ lp = (const int4*)lab + (size_t)b * (HWp / 4);

    const int nvec = HWp / 16;
    const int v0 = chunk * nvec, v1 = v0 + nvec;
    for (int v = v0 + tid; v < v1; v += 256) {
        float4 xv = xp[v];
        int4   lv = lp[v];
        atomicAdd(&lsum[clampl(lv.x)], xv.x);
        atomicAdd(&lsum[clampl(lv.y)], xv.y);
        atomicAdd(&lsum[clampl(lv.z)], xv.z);
        atomicAdd(&lsum[clampl(lv.w)], xv.w);
    }
    __syncthreads();

    float* __restrict__ dst = sums + (size_t)(b * Cd + c) * NLd;
    for (int l = tid; l < NLd; l += 256)
        atomicAdd(&dst[l], lsum[l]);
}

__global__ __launch_bounds__(256)
void fb_counts_kernel(const int* __restrict__ lab, float* __restrict__ counts) {
    __shared__ unsigned lcnt[NLd];
    const int tid   = threadIdx.x;
    const int chunk = blockIdx.x;
    const int b     = blockIdx.y;

    for (int l = tid; l < NLd; l += 256) lcnt[l] = 0u;
    __syncthreads();

    const int4* __restrict__ lp = (const int4*)lab + (size_t)b * (HWp / 4);
    const int nvec = HWp / 16;
    const int v0 = chunk * nvec, v1 = v0 + nvec;
    for (int v = v0 + tid; v < v1; v += 256) {
        int4 lv = lp[v];
        atomicAdd(&lcnt[clampl(lv.x)], 1u);
        atomicAdd(&lcnt[clampl(lv.y)], 1u);
        atomicAdd(&lcnt[clampl(lv.z)], 1u);
        atomicAdd(&lcnt[clampl(lv.w)], 1u);
    }
    __syncthreads();

    float* __restrict__ dst = counts + (size_t)b * NLd;
    for (int l = tid; l < NLd; l += 256)
        atomicAdd(&dst[l], (float)lcnt[l]);
}

__global__ __launch_bounds__(256)
void fb_gather_kernel(const float* __restrict__ sums,
                      const float* __restrict__ counts,
                      const int* __restrict__ edges,
                      const float* __restrict__ ew,
                      float* __restrict__ out) {
    const int t  = blockIdx.x * 256 + threadIdx.x;
    const int bs = t >> 6;
    const int c  = t & 63;
    const int b  = bs >> 11;

    const int la = clampl(edges[bs * 2 + 0]);
    const int lb = clampl(edges[bs * 2 + 1]);

    const float ca = fmaxf(counts[b * NLd + la], 1.0f);
    const float cb = fmaxf(counts[b * NLd + lb], 1.0f);

    const size_t plane = (size_t)(b * Cd + c) * NLd;
    out[t] = sums[plane + la] / ca;
    out[(size_t)Bd * NSd * Cd + t] = sums[plane + lb] / cb;
    if (t < Bd * NSd)
        out[2 * (size_t)Bd * NSd * Cd + t] = ew[t];
}

extern "C" void kernel_launch(void* const* d_in, const int* in_sizes, int n_in,
                              void* d_out, int out_size, void* d_ws, size_t ws_size,
                              hipStream_t stream) {
    const float* x     = (const float*)d_in[0];   // [B,C,H,W] f32
    const int*   lab   = (const int*)d_in[1];     // [B,1,H,W] i32
    const int*   edges = (const int*)d_in[2];     // [B,NS,2] i32
    const float* ew    = (const float*)d_in[3];   // [B,NS] f32
    float*       out   = (float*)d_out;

    const int n_gather = Bd * NSd * Cd;   // 524288

    if (ws_size >= (size_t)WS_ELEMS * sizeof(float)) {
        unsigned* partial  = (unsigned*)d_ws + OFF_PART;
        int*      blockCnt = (int*)d_ws + OFF_BCNT;
        int*      blockSt  = (int*)d_ws + OFF_BST;
        int*      rank     = (int*)d_ws + OFF_RANK;
        float*    means    = (float*)d_ws + OFF_MEANS;

        // no memset needed: all ws regions are fully overwritten
        rank_kernel<<<NWIN, 1024, 0, stream>>>(lab, blockCnt, blockSt, rank);
        fused_kernel<<<dim3(2, NWIN), 1024, 0, stream>>>(x, rank, blockCnt, blockSt, partial);
        combine_kernel<<<dim3(63, Bd), 256, 0, stream>>>(partial, blockCnt, means);
        gather_kernel<<<n_gather / 256, 256, 0, stream>>>(means, edges, ew, out);
    } else {
        // ---- fallback: R1 atomic path ----
        float* sums   = (float*)d_ws;
        float* counts = sums + (size_t)Bd * Cd * NLd;

        hipMemsetAsync(d_ws, 0, (size_t)WS_FB_ELEMS * sizeof(float), stream);

        fb_sums_kernel<<<dim3(4, Cd, Bd), 256, 0, stream>>>(x, lab, sums);
        fb_counts_kernel<<<dim3(4, Bd), 256, 0, stream>>>(lab, counts);
        fb_gather_kernel<<<n_gather / 256, 256, 0, stream>>>(sums, counts, edges, ew, out);
    }
}

// Round 15
// 78.359 us; speedup vs baseline: 1.0448x; 1.0448x over previous
//
#include <hip/hip_runtime.h>

// Problem constants (fixed by the reference setup)
#define Bd 4
#define Cd 64
#define HWp 262144           // 512*512 = 2^18 pixels per image
#define NSd 2048
#define NLd 1000

#define NWIN   256           // windows total (64 per image)
#define PXW    4096          // pixels per window
#define NSL    16            // channel slices (4 ch each)
#define CSL    4             // channels per slice
#define SPB    8             // slices per block (2 blocks per window)
#define PU32   2000          // u32 per partial slice-row (1000 labels x uint2)

typedef float __attribute__((ext_vector_type(4))) floatx4;

// ===========================================================================
// FAST PATH (fused, 2 blocks/CU for cross-block latency hiding) — R13 config,
// the measured optimum (78.5 us). R14's hoisted-rank variant regressed (+3.4):
// in-block sort redundancy is hidden under the stream; extra traffic is not.
//   fused  : grid (2, 256). Each block: {hist -> scan -> ranks} for its
//            window, then 8 slices {scatter bf16x4 rows to LDS -> per-label
//            lane sums -> bf16 partial store}. Two co-resident blocks
//            interleave load-stall with sum/scatter phases.
//   combine: reduce 64 windows -> means (f32 accum, fused divide)
//   gather : edge endpoint means + edge weights
// ws layout (4B units):
//   partial  [NWIN*NSL*PU32] u32    bf16-pair label sums
//   blockCnt [NWIN*NL]       int
//   means    [B*NL*C]        float
// ===========================================================================
#define OFF_PART  0
#define OFF_BCNT  (NWIN * NSL * PU32)
#define OFF_MEANS (OFF_BCNT + NWIN * NLd)
#define WS_ELEMS  (OFF_MEANS + Bd * NLd * Cd)

__device__ __forceinline__ unsigned short f2bf(float f) {
    unsigned u = __float_as_uint(f);
    u += 0x7FFFu + ((u >> 16) & 1u);          // round-to-nearest-even
    return (unsigned short)(u >> 16);
}
__device__ __forceinline__ unsigned pack2(float lo, float hi) {
    return ((unsigned)f2bf(hi) << 16) | (unsigned)f2bf(lo);
}
__device__ __forceinline__ float bflo(unsigned u) { return __uint_as_float(u << 16); }
__device__ __forceinline__ float bfhi(unsigned u) { return __uint_as_float(u & 0xFFFF0000u); }
__device__ __forceinline__ int clampl(int l) {
    return (l < 0) ? 0 : (l >= NLd ? NLd - 1 : l);
}

// ---------------------------------------------------------------------------
// 1) fused kernel. grid = (2, NWIN), block = 1024 (thread owns 4 px).
//    LDS 36KB, VGPR forced <=64 -> 2 blocks/CU co-resident.
// ---------------------------------------------------------------------------
__global__ __launch_bounds__(1024, 8)
void fused_kernel(const float* __restrict__ x, const int* __restrict__ lab,
                  int* __restrict__ blockCnt, unsigned* __restrict__ partial) {
    __shared__ int h[1024];          // hist -> scan -> cursor (reused)
    __shared__ uint2 ordered[PXW];   // 32 KB: rank-ordered bf16x4 pixel rows

    const int tid  = threadIdx.x;
    const int half = blockIdx.x;     // 0..1 (slice group)
    const int w    = blockIdx.y;     // 0..255 (window)
    const int b    = w >> 6;
    const int p0   = (w & 63) * PXW;

    h[tid] = 0;
    __syncthreads();

    const int4 lv = ((const int4*)(lab + ((size_t)b << 18) + p0))[tid];
    const int l0 = clampl(lv.x), l1 = clampl(lv.y),
              l2 = clampl(lv.z), l3 = clampl(lv.w);
    atomicAdd(&h[l0], 1);
    atomicAdd(&h[l1], 1);
    atomicAdd(&h[l2], 1);
    atomicAdd(&h[l3], 1);
    __syncthreads();

    const int myCnt = h[tid];
    if (half == 0 && tid < NLd) blockCnt[(size_t)w * NLd + tid] = myCnt;
    // in-place inclusive Hillis-Steele scan of h
    for (int off = 1; off < 1024; off <<= 1) {
        int t = (tid >= off) ? h[tid - off] : 0;
        __syncthreads();
        h[tid] += t;
        __syncthreads();
    }
    const int myst = h[tid] - myCnt;       // my label's run start
    __syncthreads();
    h[tid] = myst;                         // cursor init
    __syncthreads();

    const int r0 = atomicAdd(&h[l0], 1) & (PXW - 1);
    const int r1 = atomicAdd(&h[l1], 1) & (PXW - 1);
    const int r2 = atomicAdd(&h[l2], 1) & (PXW - 1);
    const int r3 = atomicAdd(&h[l3], 1) & (PXW - 1);

    // my slice group's channel base
    const float* __restrict__ xs =
        x + (((size_t)b * Cd + half * (SPB * CSL)) << 18) + p0 + 4 * tid;
    unsigned* __restrict__ pout =
        partial + ((size_t)w * NSL + half * SPB) * PU32;

    // prologue: load + pack local slice 0
    floatx4 v0, v1, v2, v3;
    v0 = __builtin_nontemporal_load((const floatx4*)(xs + ((size_t)0 << 18)));
    v1 = __builtin_nontemporal_load((const floatx4*)(xs + ((size_t)1 << 18)));
    v2 = __builtin_nontemporal_load((const floatx4*)(xs + ((size_t)2 << 18)));
    v3 = __builtin_nontemporal_load((const floatx4*)(xs + ((size_t)3 << 18)));
    uint2 pk0, pk1, pk2, pk3;
    pk0.x = pack2(v0[0], v1[0]); pk0.y = pack2(v2[0], v3[0]);
    pk1.x = pack2(v0[1], v1[1]); pk1.y = pack2(v2[1], v3[1]);
    pk2.x = pack2(v0[2], v1[2]); pk2.y = pack2(v2[2], v3[2]);
    pk3.x = pack2(v0[3], v1[3]); pk3.y = pack2(v2[3], v3[3]);

    for (int s = 0; s < SPB; ++s) {
        __syncthreads();                 // previous slice's sums complete
        ordered[r0] = pk0;
        ordered[r1] = pk1;
        ordered[r2] = pk2;
        ordered[r3] = pk3;
        if (s + 1 < SPB) {               // issue next slice's loads now
            const float* nb = xs + (((size_t)((s + 1) * CSL)) << 18);
            v0 = __builtin_nontemporal_load((const floatx4*)(nb + ((size_t)0 << 18)));
            v1 = __builtin_nontemporal_load((const floatx4*)(nb + ((size_t)1 << 18)));
            v2 = __builtin_nontemporal_load((const floatx4*)(nb + ((size_t)2 << 18)));
            v3 = __builtin_nontemporal_load((const floatx4*)(nb + ((size_t)3 << 18)));
        }
        __syncthreads();                 // scatter visible

        if (tid < NLd) {
            float a0 = 0, a1 = 0, a2 = 0, a3 = 0;
            for (int i = 0; i < myCnt; ++i) {
                uint2 u = ordered[(myst + i) & (PXW - 1)];
                a0 += bflo(u.x); a1 += bfhi(u.x);
                a2 += bflo(u.y); a3 += bfhi(u.y);
            }
            uint2 o; o.x = pack2(a0, a1); o.y = pack2(a2, a3);
            *(uint2*)(pout + (size_t)s * PU32 + tid * 2) = o;
        }
        if (s + 1 < SPB) {               // pack after sums (waits on loads)
            pk0.x = pack2(v0[0], v1[0]); pk0.y = pack2(v2[0], v3[0]);
            pk1.x = pack2(v0[1], v1[1]); pk1.y = pack2(v2[1], v3[1]);
            pk2.x = pack2(v0[2], v1[2]); pk2.y = pack2(v2[2], v3[2]);
            pk3.x = pack2(v0[3], v1[3]); pk3.y = pack2(v2[3], v3[3]);
        }
    }
}

// ---------------------------------------------------------------------------
// 2) combine: reduce 64 windows -> means[b][l][c], f32 accumulate.
//    grid = (63, B) x 256 thr; tid -> (s = tid>>4, ll = tid&15).
// ---------------------------------------------------------------------------
__global__ __launch_bounds__(256)
void combine_kernel(const unsigned* __restrict__ partial,
                    const int* __restrict__ blockCnt,
                    float* __restrict__ means) {
    __shared__ float ninv[16];
    const int tid = threadIdx.x;
    const int b   = blockIdx.y;
    const int l0  = blockIdx.x * 16;
    const int s   = tid >> 4;       // slice 0..15
    const int ll  = tid & 15;       // label within group
    const int l   = l0 + ll;

    if (tid < 16) {
        const int li = (l0 + tid < NLd) ? (l0 + tid) : (NLd - 1);
        int n = 0;
        for (int g = 0; g < 64; ++g)
            n += blockCnt[(size_t)(b * 64 + g) * NLd + li];
        ninv[tid] = 1.0f / (float)(n > 0 ? n : 1);
    }
    __syncthreads();

    if (l < NLd) {
        float r0 = 0, r1 = 0, r2 = 0, r3 = 0;
        const unsigned* __restrict__ pb =
            partial + ((size_t)(b * 64) * NSL + s) * PU32 + l * 2;
        for (int g = 0; g < 64; ++g) {
            uint2 p = *(const uint2*)(pb + (size_t)g * NSL * PU32);
            r0 += bflo(p.x); r1 += bfhi(p.x);
            r2 += bflo(p.y); r3 += bfhi(p.y);
        }
        const float sc = ninv[ll];
        float4 o; o.x = r0 * sc; o.y = r1 * sc; o.z = r2 * sc; o.w = r3 * sc;
        *(float4*)(means + (((size_t)(b * NLd + l)) << 6) + s * 4) = o;
    }
}

// ---------------------------------------------------------------------------
// 3) gather means at edge endpoints + copy edge weights.
// ---------------------------------------------------------------------------
__global__ __launch_bounds__(256)
void gather_kernel(const float* __restrict__ means,
                   const int* __restrict__ edges,
                   const float* __restrict__ ew,
                   float* __restrict__ out) {
    const int t  = blockIdx.x * 256 + threadIdx.x;   // 0 .. B*NS*C-1
    const int bs = t >> 6;                           // b*NS + s
    const int c  = t & 63;
    const int b  = bs >> 11;                         // NS = 2048

    const int la = clampl(edges[bs * 2 + 0]);
    const int lb = clampl(edges[bs * 2 + 1]);

    out[t] = means[((size_t)(b * NLd + la) << 6) + c];
    out[(size_t)Bd * NSd * Cd + t] = means[((size_t)(b * NLd + lb) << 6) + c];
    if (t < Bd * NSd)
        out[2 * (size_t)Bd * NSd * Cd + t] = ew[t];
}

// ===========================================================================
// FALLBACK PATH (R1 design, known-good 371 us; needs ~1 MB ws)
// ===========================================================================
#define WS_FB_ELEMS (Bd * Cd * NLd + Bd * NLd)

__global__ __launch_bounds__(256)
void fb_sums_kernel(const float* __restrict__ x, const int* __restrict__ lab,
                    float* __restrict__ sums) {
    __shared__ float lsum[NLd];
    const int tid   = threadIdx.x;
    const int chunk = blockIdx.x;
    const int c     = blockIdx.y;
    const int b     = blockIdx.z;

    for (int l = tid; l < NLd; l += 256) lsum[l] = 0.0f;
    __syncthreads();

    const float4* __restrict__ xp =
        (const float4*)x + (size_t)(b * Cd + c) * (HWp / 4);
    const int4* __restrict__ lp = (const int4*)lab + (size_t)b * (HWp / 4);

    const int nvec = HWp / 16;
    const int v0 = chunk * nvec, v1 = v0 + nvec;
    for (int v = v0 + tid; v < v1; v += 256) {
        float4 xv = xp[v];
        int4   lv = lp[v];
        atomicAdd(&lsum[clampl(lv.x)], xv.x);
        atomicAdd(&lsum[clampl(lv.y)], xv.y);
        atomicAdd(&lsum[clampl(lv.z)], xv.z);
        atomicAdd(&lsum[clampl(lv.w)], xv.w);
    }
    __syncthreads();

    float* __restrict__ dst = sums + (size_t)(b * Cd + c) * NLd;
    for (int l = tid; l < NLd; l += 256)
        atomicAdd(&dst[l], lsum[l]);
}

__global__ __launch_bounds__(256)
void fb_counts_kernel(const int* __restrict__ lab, float* __restrict__ counts) {
    __shared__ unsigned lcnt[NLd];
    const int tid   = threadIdx.x;
    const int chunk = blockIdx.x;
    const int b     = blockIdx.y;

    for (int l = tid; l < NLd; l += 256) lcnt[l] = 0u;
    __syncthreads();

    const int4* __restrict__ lp = (const int4*)lab + (size_t)b * (HWp / 4);
    const int nvec = HWp / 16;
    const int v0 = chunk * nvec, v1 = v0 + nvec;
    for (int v = v0 + tid; v < v1; v += 256) {
        int4 lv = lp[v];
        atomicAdd(&lcnt[clampl(lv.x)], 1u);
        atomicAdd(&lcnt[clampl(lv.y)], 1u);
        atomicAdd(&lcnt[clampl(lv.z)], 1u);
        atomicAdd(&lcnt[clampl(lv.w)], 1u);
    }
    __syncthreads();

    float* __restrict__ dst = counts + (size_t)b * NLd;
    for (int l = tid; l < NLd; l += 256)
        atomicAdd(&dst[l], (float)lcnt[l]);
}

__global__ __launch_bounds__(256)
void fb_gather_kernel(const float* __restrict__ sums,
                      const float* __restrict__ counts,
                      const int* __restrict__ edges,
                      const float* __restrict__ ew,
                      float* __restrict__ out) {
    const int t  = blockIdx.x * 256 + threadIdx.x;
    const int bs = t >> 6;
    const int c  = t & 63;
    const int b  = bs >> 11;

    const int la = clampl(edges[bs * 2 + 0]);
    const int lb = clampl(edges[bs * 2 + 1]);

    const float ca = fmaxf(counts[b * NLd + la], 1.0f);
    const float cb = fmaxf(counts[b * NLd + lb], 1.0f);

    const size_t plane = (size_t)(b * Cd + c) * NLd;
    out[t] = sums[plane + la] / ca;
    out[(size_t)Bd * NSd * Cd + t] = sums[plane + lb] / cb;
    if (t < Bd * NSd)
        out[2 * (size_t)Bd * NSd * Cd + t] = ew[t];
}

extern "C" void kernel_launch(void* const* d_in, const int* in_sizes, int n_in,
                              void* d_out, int out_size, void* d_ws, size_t ws_size,
                              hipStream_t stream) {
    const float* x     = (const float*)d_in[0];   // [B,C,H,W] f32
    const int*   lab   = (const int*)d_in[1];     // [B,1,H,W] i32
    const int*   edges = (const int*)d_in[2];     // [B,NS,2] i32
    const float* ew    = (const float*)d_in[3];   // [B,NS] f32
    float*       out   = (float*)d_out;

    const int n_gather = Bd * NSd * Cd;   // 524288

    if (ws_size >= (size_t)WS_ELEMS * sizeof(float)) {
        unsigned* partial  = (unsigned*)d_ws + OFF_PART;
        int*      blockCnt = (int*)d_ws + OFF_BCNT;
        float*    means    = (float*)d_ws + OFF_MEANS;

        // no memset needed: partial/blockCnt/means are fully overwritten
        fused_kernel<<<dim3(2, NWIN), 1024, 0, stream>>>(x, lab, blockCnt, partial);
        combine_kernel<<<dim3(63, Bd), 256, 0, stream>>>(partial, blockCnt, means);
        gather_kernel<<<n_gather / 256, 256, 0, stream>>>(means, edges, ew, out);
    } else {
        // ---- fallback: R1 atomic path ----
        float* sums   = (float*)d_ws;
        float* counts = sums + (size_t)Bd * Cd * NLd;

        hipMemsetAsync(d_ws, 0, (size_t)WS_FB_ELEMS * sizeof(float), stream);

        fb_sums_kernel<<<dim3(4, Cd, Bd), 256, 0, stream>>>(x, lab, sums);
        fb_counts_kernel<<<dim3(4, Bd), 256, 0, stream>>>(lab, counts);
        fb_gather_kernel<<<n_gather / 256, 256, 0, stream>>>(sums, counts, edges, ew, out);
    }
}